// Round 7
// baseline (150.666 us; speedup 1.0000x reference)
//
#include <hip/hip_runtime.h>
#include <hip/hip_bf16.h>

#define DIMF 512
#define NHEAD 8
#define DHEAD 64
#define BATCH 2
#define SEQN 2048
#define SEQM 2048
#define FPS 40        // padded LDS row stride (u16): 32 data + 8 pad -> 2-way banks
#define QSCALE 0.18033688011112042f   // 0.125 * log2(e)

typedef unsigned short u16;
typedef __attribute__((ext_vector_type(8))) short bf16x8;
typedef __attribute__((ext_vector_type(4))) float f32x4;

static __device__ __forceinline__ u16 f2bf(float f) {
    unsigned u = __float_as_uint(f);
    u += 0x7FFF + ((u >> 16) & 1);      // RNE
    return (u16)(u >> 16);
}

static __device__ __forceinline__
void load16(const u16* g, u16* l) {
    __builtin_amdgcn_global_load_lds(
        (const __attribute__((address_space(1))) void*)g,
        (__attribute__((address_space(3))) void*)l,
        16, 0, 0);
}

// permlane pair: A<32..63> <-> C<0..31>, then A<odd 16-groups> <-> C<even>.
static __device__ __forceinline__
void permpair(unsigned& a, unsigned& c) {
#if __has_builtin(__builtin_amdgcn_permlane32_swap)
    {
        auto r1 = __builtin_amdgcn_permlane32_swap(a, c, false, false);
        unsigned a1 = r1[0], c1 = r1[1];
        auto r2 = __builtin_amdgcn_permlane16_swap(a1, c1, false, false);
        a = r2[0]; c = r2[1];
    }
#else
    asm("v_permlane32_swap_b32 %0, %1" : "+v"(a), "+v"(c));
    asm("v_permlane16_swap_b32 %0, %1" : "+v"(a), "+v"(c));
#endif
}

// T12: two 32-row S^T sub-accumulators -> exp2 -> packed bf16 -> permlane
// route to the PV A-frag layout (verified index-by-index, R3 measured win).
static __device__ __forceinline__
bf16x8 t12pack(f32x4 s0, f32x4 s1) {
    float e00 = __builtin_amdgcn_exp2f(s0[0]);
    float e01 = __builtin_amdgcn_exp2f(s0[1]);
    float e02 = __builtin_amdgcn_exp2f(s0[2]);
    float e03 = __builtin_amdgcn_exp2f(s0[3]);
    float e10 = __builtin_amdgcn_exp2f(s1[0]);
    float e11 = __builtin_amdgcn_exp2f(s1[1]);
    float e12 = __builtin_amdgcn_exp2f(s1[2]);
    float e13 = __builtin_amdgcn_exp2f(s1[3]);
    unsigned a0, a1, c0w, c1w;
    asm("v_cvt_pk_bf16_f32 %0, %1, %2" : "=v"(a0)  : "v"(e00), "v"(e01));
    asm("v_cvt_pk_bf16_f32 %0, %1, %2" : "=v"(a1)  : "v"(e02), "v"(e03));
    asm("v_cvt_pk_bf16_f32 %0, %1, %2" : "=v"(c0w) : "v"(e10), "v"(e11));
    asm("v_cvt_pk_bf16_f32 %0, %1, %2" : "=v"(c1w) : "v"(e12), "v"(e13));
    permpair(a0, c0w);   // a0 = frag w0, c0w = frag w2
    permpair(a1, c1w);   // a1 = frag w1, c1w = frag w3
    union { unsigned u[4]; bf16x8 hv; } pu;
    pu.u[0] = a0; pu.u[1] = a1; pu.u[2] = c0w; pu.u[3] = c1w;
    return pu.hv;
}

// Barrier WITHOUT vmcnt drain (GEMM K-loop: cross-wave data moves via LDS
// only; register-staged global loads are ordered by compiler register deps).
#define LDS_BARRIER() do {                                      \
    asm volatile("s_waitcnt lgkmcnt(0)" ::: "memory");          \
    __builtin_amdgcn_s_barrier();                               \
    __builtin_amdgcn_sched_barrier(0);                          \
} while (0)

// ---------------------------------------------------------------------------
// weights fp32 -> bf16 (+ mask int -> bf16 {0,1})
// ---------------------------------------------------------------------------
__global__ __launch_bounds__(256)
void cvt_w(const float* __restrict__ wq, const float* __restrict__ wk,
           const float* __restrict__ wv, const float* __restrict__ wm,
           const int* __restrict__ mask,
           u16* __restrict__ wqb, u16* __restrict__ wkb,
           u16* __restrict__ wvb, u16* __restrict__ wmb,
           u16* __restrict__ maskbf)
{
    int i = (blockIdx.x * 256 + threadIdx.x) * 4;
    if (blockIdx.y == 4) {
        if (i < BATCH * SEQM) {
            int4 m4 = *(const int4*)&mask[i];
            *(ushort4*)&maskbf[i] = make_ushort4(m4.x ? 0x3F80 : 0, m4.y ? 0x3F80 : 0,
                                                 m4.z ? 0x3F80 : 0, m4.w ? 0x3F80 : 0);
        }
        return;
    }
    const float* in = (blockIdx.y == 0) ? wq : (blockIdx.y == 1) ? wk
                    : (blockIdx.y == 2) ? wv : wm;
    u16* out = (blockIdx.y == 0) ? wqb : (blockIdx.y == 1) ? wkb
             : (blockIdx.y == 2) ? wvb : wmb;
    if (i >= DIMF * DIMF) return;
    float4 v = *(const float4*)&in[i];
    *(ushort4*)&out[i] = make_ushort4(f2bf(v.x), f2bf(v.y), f2bf(v.z), f2bf(v.w));
}

// ---------------------------------------------------------------------------
// bf16 MFMA GEMM (R3-proven): double-buffered, one lgkm-only barrier per
// K-step.  64x128 tile, 4 waves (2x2), wave 32x64 = 2x4 frags.  A from fp32
// (fused cvt) or bf16.  Padded LDS stride 40 u16 (2-way banks).
// mode 0: q -> bf16 [B][H][n][d], (val+bias)*QSCALE (softmax+exp2 folded)
// mode 1: k -> bf16 [B][H][m][d]
// mode 2: V^T -> bf16 [B][H][d][m], masked rows zeroed, transposed in-block
// mode 3: fp32 row-major [4096][512]
// ---------------------------------------------------------------------------
#define ASZ (64 * FPS)
#define BSZ (128 * FPS)

__device__ __forceinline__
void gemm_mfma(const float* __restrict__ Xf, const u16* __restrict__ Xb,
               const u16* __restrict__ W, const float* __restrict__ bias,
               const int* __restrict__ msk, void* __restrict__ Out, int mode)
{
    __shared__ __align__(16) u16 SH[2 * ASZ + 2 * BSZ];   // 30 KB

    const int tid  = threadIdx.x;
    const int wave = tid >> 6;
    const int lane = tid & 63;
    const int l15  = lane & 15;
    const int quad = lane >> 4;
    const int wm = wave & 1, wn = wave >> 1;
    const int r0 = blockIdx.x * 64, c0 = blockIdx.y * 128;

    f32x4 acc[2][4] = {};

    const int br = tid >> 2, boct = tid & 3;        // B: rows br, br+64
    const int ar = tid >> 3, aseg = tid & 7;        // A fp32: rows ar, ar+32

    bf16x8 rb0, rb1, rab;
    float4 ra0, ra1;

    auto loadg = [&](int k0) {
        rb0 = *(const bf16x8*)&W[(size_t)(c0 + br) * DIMF + k0 + boct * 8];
        rb1 = *(const bf16x8*)&W[(size_t)(c0 + br + 64) * DIMF + k0 + boct * 8];
        if (Xf) {
            ra0 = *(const float4*)&Xf[(size_t)(r0 + ar) * DIMF + k0 + aseg * 4];
            ra1 = *(const float4*)&Xf[(size_t)(r0 + ar + 32) * DIMF + k0 + aseg * 4];
        } else {
            rab = *(const bf16x8*)&Xb[(size_t)(r0 + br) * DIMF + k0 + boct * 8];
        }
    };
    auto stage = [&](int buf) {
        u16* As = SH + buf * ASZ;
        u16* Bs = SH + 2 * ASZ + buf * BSZ;
        if (Xf) {
            *(ushort4*)&As[ar * FPS + aseg * 4] =
                make_ushort4(f2bf(ra0.x), f2bf(ra0.y), f2bf(ra0.z), f2bf(ra0.w));
            *(ushort4*)&As[(ar + 32) * FPS + aseg * 4] =
                make_ushort4(f2bf(ra1.x), f2bf(ra1.y), f2bf(ra1.z), f2bf(ra1.w));
        } else {
            *(bf16x8*)&As[br * FPS + boct * 8] = rab;
        }
        *(bf16x8*)&Bs[br * FPS + boct * 8] = rb0;
        *(bf16x8*)&Bs[(br + 64) * FPS + boct * 8] = rb1;
    };

    loadg(0);
    stage(0);
    loadg(32);
    LDS_BARRIER();

    const int NK = DIMF / 32;   // 16
    for (int kt = 0; kt < NK; ++kt) {
        const int cur = kt & 1;
        if (kt + 1 < NK) stage(cur ^ 1);       // regs for kt+1 (vmcnt per-reg)
        if (kt + 2 < NK) loadg((kt + 2) * 32); // rides through next barrier
        const u16* As = SH + cur * ASZ;
        const u16* Bs = SH + 2 * ASZ + cur * BSZ;

        bf16x8 af[2], bf[4];
        #pragma unroll
        for (int mi = 0; mi < 2; ++mi)
            af[mi] = *(const bf16x8*)&As[(wm * 32 + mi * 16 + l15) * FPS + quad * 8];
        #pragma unroll
        for (int ni = 0; ni < 4; ++ni)
            bf[ni] = *(const bf16x8*)&Bs[(wn * 64 + ni * 16 + l15) * FPS + quad * 8];
        #pragma unroll
        for (int mi = 0; mi < 2; ++mi)
            #pragma unroll
            for (int ni = 0; ni < 4; ++ni)
                acc[mi][ni] = __builtin_amdgcn_mfma_f32_16x16x32_bf16(
                    af[mi], bf[ni], acc[mi][ni], 0, 0, 0);
        LDS_BARRIER();   // lgkm-only: buf[cur] reads done, buf[cur^1] full
    }

    float bb[4];
    #pragma unroll
    for (int ni = 0; ni < 4; ++ni)
        bb[ni] = bias[c0 + wn * 64 + ni * 16 + l15];

    if (mode == 2) {
        u16* T = SH;                         // 64 x 72 u16 (9 KB of 30)
        const int b = r0 >> 11;
        const int n_base = r0 & (SEQN - 1);
        #pragma unroll
        for (int hh = 0; hh < 2; ++hh) {
            __syncthreads();
            if (wn == hh) {
                #pragma unroll
                for (int mi = 0; mi < 2; ++mi) {
                    const int rl = wm * 32 + mi * 16 + quad * 4;
                    int4 m4 = *(const int4*)&msk[b * SEQM + n_base + rl];
                    float mm[4];
                    mm[0] = m4.x ? 1.f : 0.f; mm[1] = m4.y ? 1.f : 0.f;
                    mm[2] = m4.z ? 1.f : 0.f; mm[3] = m4.w ? 1.f : 0.f;
                    #pragma unroll
                    for (int ni = 0; ni < 4; ++ni)
                        #pragma unroll
                        for (int r = 0; r < 4; ++r)
                            T[(rl + r) * 72 + ni * 16 + l15] =
                                f2bf((acc[mi][ni][r] + bb[ni]) * mm[r]);
                }
            }
            __syncthreads();
            const int d = tid >> 2, ms = (tid & 3) << 4;
            u16 tmp[16];
            #pragma unroll
            for (int j = 0; j < 16; ++j) tmp[j] = T[(ms + j) * 72 + d];
            const int hgl = (c0 >> 6) + hh;
            u16* dst = (u16*)Out + ((size_t)(b * NHEAD + hgl) * DHEAD + d) * SEQM
                       + n_base + ms;
            *(bf16x8*)&dst[0] = *(bf16x8*)&tmp[0];
            *(bf16x8*)&dst[8] = *(bf16x8*)&tmp[8];
        }
        return;
    }

    #pragma unroll
    for (int mi = 0; mi < 2; ++mi) {
        const int Rbase = r0 + wm * 32 + mi * 16 + quad * 4;   // +r, r=0..3
        const int b = Rbase >> 11;
        const int nb = Rbase & (SEQN - 1);
        #pragma unroll
        for (int ni = 0; ni < 4; ++ni) {
            const int C = c0 + wn * 64 + ni * 16 + l15;
            const int h = C >> 6, d = C & 63;
            if (mode == 0) {
                u16* ow = (u16*)Out;
                #pragma unroll
                for (int r = 0; r < 4; ++r)
                    ow[(((size_t)(b * NHEAD + h) * SEQN) + nb + r) * DHEAD + d] =
                        f2bf((acc[mi][ni][r] + bb[ni]) * QSCALE);
            } else if (mode == 1) {
                u16* ow = (u16*)Out;
                #pragma unroll
                for (int r = 0; r < 4; ++r)
                    ow[(((size_t)(b * NHEAD + h) * SEQN) + nb + r) * DHEAD + d] =
                        f2bf(acc[mi][ni][r] + bb[ni]);
            } else {
                float* ow = (float*)Out;
                #pragma unroll
                for (int r = 0; r < 4; ++r)
                    ow[(size_t)(Rbase + r) * DIMF + C] = acc[mi][ni][r] + bb[ni];
            }
        }
    }
}

__global__ __launch_bounds__(256, 3)
void qkv_proj(const float* __restrict__ x, const float* __restrict__ src,
              const u16* __restrict__ wqb, const float* __restrict__ bq,
              const u16* __restrict__ wkb, const float* __restrict__ bk,
              const u16* __restrict__ wvb, const float* __restrict__ bv,
              const int* __restrict__ mask,
              u16* __restrict__ qw, u16* __restrict__ kw, u16* __restrict__ vtw)
{
    const int z = blockIdx.z;
    const float* X = (z == 0) ? x : src;
    const u16* W = (z == 0) ? wqb : (z == 1) ? wkb : wvb;
    const float* B = (z == 0) ? bq : (z == 1) ? bk : bv;
    void* O = (z == 0) ? (void*)qw : (z == 1) ? (void*)kw : (void*)vtw;
    gemm_mfma(X, nullptr, W, B, mask, O, z);
}

__global__ __launch_bounds__(256, 3)
void out_proj(const u16* __restrict__ aggb, const u16* __restrict__ wmb,
              const float* __restrict__ bm, float* __restrict__ out)
{
    gemm_mfma(nullptr, aggb, wmb, bm, nullptr, (void*)out, 3);
}

// ---------------------------------------------------------------------------
// MFMA flash attention v11: v10 (KVBLK=128, R6-proven) with V DIRECT FROM
// GLOBAL.  R6 measured per-barrier convoy cost ~375cy -> further barrier
// halving is marginal; the remaining per-iter cost is the serial chain
// {barrier -> 8 K-ds_read + 8 V-ds_read -> QK -> t12 -> PV} plus the 8-load
// DMA drain.  The V swizzle algebra unwinds to a clean global address
// (vfA/B[sd] = Vt[16sd+l15][mt*128 + 64mh + 8quad (+32)]), and V is
// L2-resident (256KB/(b,h), XCD-pinned).  So: V-frags become LOOP-LOCAL
// registers loaded right after the barrier, consumed ~1000cy later at PV --
// latency covered by QK+t12.  Unlike R5 (which register-buffered K AND V
// across iterations behind lambda arrays at VGPR=84, sinking the loads),
// this keeps K in LDS/DMA unchanged and adds only 8 in-flight loads with
// static indexing.  DMA batch halves (4 load16/wave) -> shorter drain;
// 8 ds_reads leave the chain; LDS 64->32KB -> 3 blocks/CU
// (__launch_bounds__(256,3) caps VGPR at 168 to prevent R5-style sinking).
// ---------------------------------------------------------------------------
__global__ __launch_bounds__(256, 3)
void flash_attn_mfma(const u16* __restrict__ q, const u16* __restrict__ k,
                     const u16* __restrict__ vt, const u16* __restrict__ maskbf,
                     u16* __restrict__ agg)
{
    __shared__ __align__(16) u16 KsD[2][8192];    // 2 x 16 KB: 128 rows x 64 u16
    float* Osum = (float*)&KsD[0][0];             // epilogue union (16 KB)
    __shared__ float Lsum[64];

    const int tid  = threadIdx.x;
    const int wave = tid >> 6;
    const int lane = tid & 63;
    const int l15  = lane & 15;
    const int quad = lane >> 4;
    const int qg = wave >> 1, mh = wave & 1;

    // XCD swizzle: bid&7 = XCD (dispatch round-robins blocks over 8 XCDs)
    const int bid  = blockIdx.x;
    const int xcd  = bid & 7, slot = bid >> 3;        // slot 0..63
    const int pair = (xcd << 1) | (slot & 1);         // (b*8+h) 0..15
    const int b = pair >> 3, h = pair & 7;
    const int n0 = (slot >> 1) * 64;

    const size_t hoff = (size_t)(b * NHEAD + h) * (size_t)SEQM * DHEAD;
    const u16* kb = k  + hoff;
    const u16* vb = vt + hoff;
    const u16* mb = maskbf + b * SEQM;

    // K DMA: tile 128 rows x 128B, groups of 8 rows (1KB), lane l -> row
    // 8g+(l>>3), stored pos l&7 holds source oct (l&7)^(row&7).
    const int dr  = lane >> 3;
    const int kct = (lane & 7) ^ (dr & 7);
    const u16* kq[4];
    #pragma unroll
    for (int j = 0; j < 4; ++j) {
        const int g = wave + 4 * j;
        kq[j] = kb + (size_t)(g * 8 + dr) * DHEAD + kct * 8;
    }

    // Q B-frags (prescaled by 0.125*log2e): cols q = n0 + qg*32 + qh*16 + l15
    bf16x8 qf[2][2];
    #pragma unroll
    for (int qh = 0; qh < 2; ++qh) {
        const u16* qp = q + hoff + (size_t)(n0 + qg * 32 + qh * 16 + l15) * DHEAD
                        + quad * 8;
        qf[qh][0] = *(const bf16x8*)qp;
        qf[qh][1] = *(const bf16x8*)(qp + 32);
    }

    // prologue: K tile 0 -> buffer 0; mask frags 0 -> registers
    #pragma unroll
    for (int j = 0; j < 4; ++j)
        load16(kq[j], &KsD[0][(wave + 4 * j) * 512]);
    bf16x8 mfA_nxt = *(const bf16x8*)&mb[64 * mh + quad * 8];
    bf16x8 mfB_nxt = *(const bf16x8*)&mb[64 * mh + 32 + quad * 8];

    f32x4 O[2][4] = {};    // [qh][sd]: row q = quad*4+r, col d = 16*sd+l15
    f32x4 lacc[2] = {};
    const int NT = SEQM / 128;   // 16
    // per-wave V base: row d = 16sd+l15, col = mt*128 + 64mh + 8quad (+32 for B)
    const u16* vw0 = vb + (size_t)l15 * SEQM + 64 * mh + 8 * quad;

    for (int mt = 0; mt < NT; ++mt) {
        const int cur = mt & 1;
        __syncthreads();   // drains vmcnt -> K tile mt resident; prior reads done
        bf16x8 mfA = mfA_nxt, mfB = mfB_nxt;
        if (mt + 1 < NT) {
            const size_t m1 = (size_t)(mt + 1) * 128;
            const int nb = cur ^ 1;
            #pragma unroll
            for (int j = 0; j < 4; ++j)
                load16(kq[j] + m1 * DHEAD, &KsD[nb][(wave + 4 * j) * 512]);
            mfA_nxt = *(const bf16x8*)&mb[m1 + 64 * mh + quad * 8];
            mfB_nxt = *(const bf16x8*)&mb[m1 + 64 * mh + 32 + quad * 8];
        }

        // V direct-from-global for THIS tile: issued here, consumed at PV
        // (~1000cy later) -> L2 latency hidden under QK + t12.
        bf16x8 vfA[4], vfB[4];
        {
            const u16* vp = vw0 + (size_t)mt * 128;
            #pragma unroll
            for (int sd = 0; sd < 4; ++sd) {
                vfA[sd] = *(const bf16x8*)(vp + (size_t)(16 * sd) * SEQM);
                vfB[sd] = *(const bf16x8*)(vp + (size_t)(16 * sd) * SEQM + 32);
            }
        }

        const u16* Ks = KsD[cur];

        // S^T (this wave's 64-m half): st[qh][sub], mrow = 64mh+16sub+l15
        f32x4 st[2][4] = {};
        __builtin_amdgcn_s_setprio(1);
        #pragma unroll
        for (int sub = 0; sub < 4; ++sub) {
            const int mrow = 64 * mh + 16 * sub + l15;
            #pragma unroll
            for (int c = 0; c < 2; ++c) {
                const int oct = (4 * c + quad) ^ (l15 & 7);
                bf16x8 af = *(const bf16x8*)&Ks[mrow * 64 + oct * 8];
                #pragma unroll
                for (int qh = 0; qh < 2; ++qh)
                    st[qh][sub] = __builtin_amdgcn_mfma_f32_16x16x32_bf16(
                        af, qf[qh][c], st[qh][sub], 0, 0, 0);
            }
        }
        __builtin_amdgcn_s_setprio(0);

        // T12 per 32-m group
        bf16x8 pfrA[2], pfrB[2];
        #pragma unroll
        for (int qh = 0; qh < 2; ++qh) {
            pfrA[qh] = t12pack(st[qh][0], st[qh][1]);
            pfrB[qh] = t12pack(st[qh][2], st[qh][3]);
        }

        __builtin_amdgcn_s_setprio(1);
        #pragma unroll
        for (int qh = 0; qh < 2; ++qh) {
            lacc[qh] = __builtin_amdgcn_mfma_f32_16x16x32_bf16(
                pfrA[qh], mfA, lacc[qh], 0, 0, 0);
            lacc[qh] = __builtin_amdgcn_mfma_f32_16x16x32_bf16(
                pfrB[qh], mfB, lacc[qh], 0, 0, 0);
        }
        #pragma unroll
        for (int sd = 0; sd < 4; ++sd)
            #pragma unroll
            for (int qh = 0; qh < 2; ++qh) {
                O[qh][sd] = __builtin_amdgcn_mfma_f32_16x16x32_bf16(
                    pfrA[qh], vfA[sd], O[qh][sd], 0, 0, 0);
                O[qh][sd] = __builtin_amdgcn_mfma_f32_16x16x32_bf16(
                    pfrB[qh], vfB[sd], O[qh][sd], 0, 0, 0);
            }
        __builtin_amdgcn_s_setprio(0);
    }

    // combine m-halves per q-group (LDS unioned over dead KsD)
    __syncthreads();
    if (mh == 1) {
        #pragma unroll
        for (int qh = 0; qh < 2; ++qh) {
            #pragma unroll
            for (int sd = 0; sd < 4; ++sd)
                #pragma unroll
                for (int r = 0; r < 4; ++r)
                    Osum[qg * 2048 + (qh * 16 + quad * 4 + r) * 64 + 16 * sd + l15]
                        = O[qh][sd][r];
            if (l15 == 0) {
                #pragma unroll
                for (int r = 0; r < 4; ++r)
                    Lsum[qg * 32 + qh * 16 + quad * 4 + r] = lacc[qh][r];
            }
        }
    }
    __syncthreads();
    if (mh == 0) {
        #pragma unroll
        for (int qh = 0; qh < 2; ++qh)
            #pragma unroll
            for (int r = 0; r < 4; ++r) {
                const float inv = 1.f /
                    (lacc[qh][r] + Lsum[qg * 32 + qh * 16 + quad * 4 + r]);
                const int n = n0 + qg * 32 + qh * 16 + quad * 4 + r;
                u16* ag = agg + ((size_t)b * SEQN + n) * DIMF + h * DHEAD + l15;
                #pragma unroll
                for (int sd = 0; sd < 4; ++sd)
                    ag[16 * sd] = f2bf((O[qh][sd][r] +
                        Osum[qg * 2048 + (qh * 16 + quad * 4 + r) * 64 + 16 * sd + l15])
                        * inv);
            }
    }
}

extern "C" void kernel_launch(void* const* d_in, const int* in_sizes, int n_in,
                              void* d_out, int out_size, void* d_ws, size_t ws_size,
                              hipStream_t stream)
{
    (void)in_sizes; (void)n_in; (void)out_size; (void)ws_size;
    const float* x      = (const float*)d_in[0];
    const float* source = (const float*)d_in[1];
    const int*   mask   = (const int*)  d_in[2];
    const float* Wq = (const float*)d_in[3]; const float* bq = (const float*)d_in[4];
    const float* Wk = (const float*)d_in[5]; const float* bk = (const float*)d_in[6];
    const float* Wv = (const float*)d_in[7]; const float* bv = (const float*)d_in[8];
    const float* Wm = (const float*)d_in[9]; const float* bm = (const float*)d_in[10];
    float* out = (float*)d_out;

    const size_t SZ = (size_t)BATCH * SEQN * DIMF;   // 2,097,152 elems
    const size_t WZ = (size_t)DIMF * DIMF;
    u16* qw   = (u16*)d_ws;          // bf16 [B][H][n][d] (xQSCALE, +bq)
    u16* kw   = qw  + SZ;            // bf16 [B][H][m][d]
    u16* vtw  = kw  + SZ;            // bf16 V^T [B][H][d][m], masked
    u16* aggb = vtw + SZ;            // bf16 [B][n][H*64+d]
    u16* wqb  = aggb + SZ;
    u16* wkb  = wqb + WZ;
    u16* wvb  = wkb + WZ;
    u16* wmb  = wvb + WZ;
    u16* maskbf = wmb + WZ;          // bf16 [B][M] {0,1}; ~19 MB total

    dim3 gcvt((WZ / 4 + 255) / 256, 5);
    cvt_w<<<gcvt, 256, 0, stream>>>(Wq, Wk, Wv, Wm, mask,
                                    wqb, wkb, wvb, wmb, maskbf);

    dim3 gproj(4096 / 64, 512 / 128, 3);    // 768 blocks
    qkv_proj<<<gproj, 256, 0, stream>>>(x, source, wqb, bq, wkb, bk, wvb, bv,
                                        mask, qw, kw, vtw);

    flash_attn_mfma<<<512, 256, 0, stream>>>(qw, kw, vtw, maskbf, aggb);

    dim3 gout(4096 / 64, 512 / 128);        // 256 blocks
    out_proj<<<gout, 256, 0, stream>>>(aggb, wmb, bm, out);
}

// Round 8
// 138.456 us; speedup vs baseline: 1.0882x; 1.0882x over previous
//
#include <hip/hip_runtime.h>
#include <hip/hip_bf16.h>

#define DIMF 512
#define NHEAD 8
#define DHEAD 64
#define BATCH 2
#define SEQN 2048
#define SEQM 2048
#define FPS 40        // padded LDS row stride (u16): 32 data + 8 pad -> 2-way banks
#define QSCALE 0.18033688011112042f   // 0.125 * log2(e)

typedef unsigned short u16;
typedef __attribute__((ext_vector_type(8))) short bf16x8;
typedef __attribute__((ext_vector_type(4))) float f32x4;

static __device__ __forceinline__ u16 f2bf(float f) {
    unsigned u = __float_as_uint(f);
    u += 0x7FFF + ((u >> 16) & 1);      // RNE
    return (u16)(u >> 16);
}

static __device__ __forceinline__
void load16(const u16* g, u16* l) {
    __builtin_amdgcn_global_load_lds(
        (const __attribute__((address_space(1))) void*)g,
        (__attribute__((address_space(3))) void*)l,
        16, 0, 0);
}

// permlane pair: A<32..63> <-> C<0..31>, then A<odd 16-groups> <-> C<even>.
static __device__ __forceinline__
void permpair(unsigned& a, unsigned& c) {
#if __has_builtin(__builtin_amdgcn_permlane32_swap)
    {
        auto r1 = __builtin_amdgcn_permlane32_swap(a, c, false, false);
        unsigned a1 = r1[0], c1 = r1[1];
        auto r2 = __builtin_amdgcn_permlane16_swap(a1, c1, false, false);
        a = r2[0]; c = r2[1];
    }
#else
    asm("v_permlane32_swap_b32 %0, %1" : "+v"(a), "+v"(c));
    asm("v_permlane16_swap_b32 %0, %1" : "+v"(a), "+v"(c));
#endif
}

// T12: two 32-row S^T sub-accumulators -> exp2 -> packed bf16 -> permlane
// route to the PV A-frag layout (verified index-by-index, R3 measured win).
static __device__ __forceinline__
bf16x8 t12pack(f32x4 s0, f32x4 s1) {
    float e00 = __builtin_amdgcn_exp2f(s0[0]);
    float e01 = __builtin_amdgcn_exp2f(s0[1]);
    float e02 = __builtin_amdgcn_exp2f(s0[2]);
    float e03 = __builtin_amdgcn_exp2f(s0[3]);
    float e10 = __builtin_amdgcn_exp2f(s1[0]);
    float e11 = __builtin_amdgcn_exp2f(s1[1]);
    float e12 = __builtin_amdgcn_exp2f(s1[2]);
    float e13 = __builtin_amdgcn_exp2f(s1[3]);
    unsigned a0, a1, c0w, c1w;
    asm("v_cvt_pk_bf16_f32 %0, %1, %2" : "=v"(a0)  : "v"(e00), "v"(e01));
    asm("v_cvt_pk_bf16_f32 %0, %1, %2" : "=v"(a1)  : "v"(e02), "v"(e03));
    asm("v_cvt_pk_bf16_f32 %0, %1, %2" : "=v"(c0w) : "v"(e10), "v"(e11));
    asm("v_cvt_pk_bf16_f32 %0, %1, %2" : "=v"(c1w) : "v"(e12), "v"(e13));
    permpair(a0, c0w);   // a0 = frag w0, c0w = frag w2
    permpair(a1, c1w);   // a1 = frag w1, c1w = frag w3
    union { unsigned u[4]; bf16x8 hv; } pu;
    pu.u[0] = a0; pu.u[1] = a1; pu.u[2] = c0w; pu.u[3] = c1w;
    return pu.hv;
}

// Barrier WITHOUT vmcnt drain (GEMM K-loop: cross-wave data moves via LDS
// only; register-staged global loads are ordered by compiler register deps).
#define LDS_BARRIER() do {                                      \
    asm volatile("s_waitcnt lgkmcnt(0)" ::: "memory");          \
    __builtin_amdgcn_s_barrier();                               \
    __builtin_amdgcn_sched_barrier(0);                          \
} while (0)

// ---------------------------------------------------------------------------
// weights fp32 -> bf16 (+ mask int -> bf16 {0,1})
// ---------------------------------------------------------------------------
__global__ __launch_bounds__(256)
void cvt_w(const float* __restrict__ wq, const float* __restrict__ wk,
           const float* __restrict__ wv, const float* __restrict__ wm,
           const int* __restrict__ mask,
           u16* __restrict__ wqb, u16* __restrict__ wkb,
           u16* __restrict__ wvb, u16* __restrict__ wmb,
           u16* __restrict__ maskbf)
{
    int i = (blockIdx.x * 256 + threadIdx.x) * 4;
    if (blockIdx.y == 4) {
        if (i < BATCH * SEQM) {
            int4 m4 = *(const int4*)&mask[i];
            *(ushort4*)&maskbf[i] = make_ushort4(m4.x ? 0x3F80 : 0, m4.y ? 0x3F80 : 0,
                                                 m4.z ? 0x3F80 : 0, m4.w ? 0x3F80 : 0);
        }
        return;
    }
    const float* in = (blockIdx.y == 0) ? wq : (blockIdx.y == 1) ? wk
                    : (blockIdx.y == 2) ? wv : wm;
    u16* out = (blockIdx.y == 0) ? wqb : (blockIdx.y == 1) ? wkb
             : (blockIdx.y == 2) ? wvb : wmb;
    if (i >= DIMF * DIMF) return;
    float4 v = *(const float4*)&in[i];
    *(ushort4*)&out[i] = make_ushort4(f2bf(v.x), f2bf(v.y), f2bf(v.z), f2bf(v.w));
}

// ---------------------------------------------------------------------------
// bf16 MFMA GEMM (R3-proven): double-buffered, one lgkm-only barrier per
// K-step.  64x128 tile, 4 waves (2x2), wave 32x64 = 2x4 frags.  A from fp32
// (fused cvt) or bf16.  Padded LDS stride 40 u16 (2-way banks).
// mode 0: q -> bf16 [B][H][n][d], (val+bias)*QSCALE (softmax+exp2 folded)
// mode 1: k -> bf16 [B][H][m][d]
// mode 2: V^T -> bf16 [B][H][d][m], masked rows zeroed, transposed in-block
// mode 3: fp32 row-major [4096][512]
// ---------------------------------------------------------------------------
#define ASZ (64 * FPS)
#define BSZ (128 * FPS)

__device__ __forceinline__
void gemm_mfma(const float* __restrict__ Xf, const u16* __restrict__ Xb,
               const u16* __restrict__ W, const float* __restrict__ bias,
               const int* __restrict__ msk, void* __restrict__ Out, int mode)
{
    __shared__ __align__(16) u16 SH[2 * ASZ + 2 * BSZ];   // 30 KB

    const int tid  = threadIdx.x;
    const int wave = tid >> 6;
    const int lane = tid & 63;
    const int l15  = lane & 15;
    const int quad = lane >> 4;
    const int wm = wave & 1, wn = wave >> 1;
    const int r0 = blockIdx.x * 64, c0 = blockIdx.y * 128;

    f32x4 acc[2][4] = {};

    const int br = tid >> 2, boct = tid & 3;        // B: rows br, br+64
    const int ar = tid >> 3, aseg = tid & 7;        // A fp32: rows ar, ar+32

    bf16x8 rb0, rb1, rab;
    float4 ra0, ra1;

    auto loadg = [&](int k0) {
        rb0 = *(const bf16x8*)&W[(size_t)(c0 + br) * DIMF + k0 + boct * 8];
        rb1 = *(const bf16x8*)&W[(size_t)(c0 + br + 64) * DIMF + k0 + boct * 8];
        if (Xf) {
            ra0 = *(const float4*)&Xf[(size_t)(r0 + ar) * DIMF + k0 + aseg * 4];
            ra1 = *(const float4*)&Xf[(size_t)(r0 + ar + 32) * DIMF + k0 + aseg * 4];
        } else {
            rab = *(const bf16x8*)&Xb[(size_t)(r0 + br) * DIMF + k0 + boct * 8];
        }
    };
    auto stage = [&](int buf) {
        u16* As = SH + buf * ASZ;
        u16* Bs = SH + 2 * ASZ + buf * BSZ;
        if (Xf) {
            *(ushort4*)&As[ar * FPS + aseg * 4] =
                make_ushort4(f2bf(ra0.x), f2bf(ra0.y), f2bf(ra0.z), f2bf(ra0.w));
            *(ushort4*)&As[(ar + 32) * FPS + aseg * 4] =
                make_ushort4(f2bf(ra1.x), f2bf(ra1.y), f2bf(ra1.z), f2bf(ra1.w));
        } else {
            *(bf16x8*)&As[br * FPS + boct * 8] = rab;
        }
        *(bf16x8*)&Bs[br * FPS + boct * 8] = rb0;
        *(bf16x8*)&Bs[(br + 64) * FPS + boct * 8] = rb1;
    };

    loadg(0);
    stage(0);
    loadg(32);
    LDS_BARRIER();

    const int NK = DIMF / 32;   // 16
    for (int kt = 0; kt < NK; ++kt) {
        const int cur = kt & 1;
        if (kt + 1 < NK) stage(cur ^ 1);       // regs for kt+1 (vmcnt per-reg)
        if (kt + 2 < NK) loadg((kt + 2) * 32); // rides through next barrier
        const u16* As = SH + cur * ASZ;
        const u16* Bs = SH + 2 * ASZ + cur * BSZ;

        bf16x8 af[2], bf[4];
        #pragma unroll
        for (int mi = 0; mi < 2; ++mi)
            af[mi] = *(const bf16x8*)&As[(wm * 32 + mi * 16 + l15) * FPS + quad * 8];
        #pragma unroll
        for (int ni = 0; ni < 4; ++ni)
            bf[ni] = *(const bf16x8*)&Bs[(wn * 64 + ni * 16 + l15) * FPS + quad * 8];
        #pragma unroll
        for (int mi = 0; mi < 2; ++mi)
            #pragma unroll
            for (int ni = 0; ni < 4; ++ni)
                acc[mi][ni] = __builtin_amdgcn_mfma_f32_16x16x32_bf16(
                    af[mi], bf[ni], acc[mi][ni], 0, 0, 0);
        LDS_BARRIER();   // lgkm-only: buf[cur] reads done, buf[cur^1] full
    }

    float bb[4];
    #pragma unroll
    for (int ni = 0; ni < 4; ++ni)
        bb[ni] = bias[c0 + wn * 64 + ni * 16 + l15];

    if (mode == 2) {
        u16* T = SH;                         // 64 x 72 u16 (9 KB of 30)
        const int b = r0 >> 11;
        const int n_base = r0 & (SEQN - 1);
        #pragma unroll
        for (int hh = 0; hh < 2; ++hh) {
            __syncthreads();
            if (wn == hh) {
                #pragma unroll
                for (int mi = 0; mi < 2; ++mi) {
                    const int rl = wm * 32 + mi * 16 + quad * 4;
                    int4 m4 = *(const int4*)&msk[b * SEQM + n_base + rl];
                    float mm[4];
                    mm[0] = m4.x ? 1.f : 0.f; mm[1] = m4.y ? 1.f : 0.f;
                    mm[2] = m4.z ? 1.f : 0.f; mm[3] = m4.w ? 1.f : 0.f;
                    #pragma unroll
                    for (int ni = 0; ni < 4; ++ni)
                        #pragma unroll
                        for (int r = 0; r < 4; ++r)
                            T[(rl + r) * 72 + ni * 16 + l15] =
                                f2bf((acc[mi][ni][r] + bb[ni]) * mm[r]);
                }
            }
            __syncthreads();
            const int d = tid >> 2, ms = (tid & 3) << 4;
            u16 tmp[16];
            #pragma unroll
            for (int j = 0; j < 16; ++j) tmp[j] = T[(ms + j) * 72 + d];
            const int hgl = (c0 >> 6) + hh;
            u16* dst = (u16*)Out + ((size_t)(b * NHEAD + hgl) * DHEAD + d) * SEQM
                       + n_base + ms;
            *(bf16x8*)&dst[0] = *(bf16x8*)&tmp[0];
            *(bf16x8*)&dst[8] = *(bf16x8*)&tmp[8];
        }
        return;
    }

    #pragma unroll
    for (int mi = 0; mi < 2; ++mi) {
        const int Rbase = r0 + wm * 32 + mi * 16 + quad * 4;   // +r, r=0..3
        const int b = Rbase >> 11;
        const int nb = Rbase & (SEQN - 1);
        #pragma unroll
        for (int ni = 0; ni < 4; ++ni) {
            const int C = c0 + wn * 64 + ni * 16 + l15;
            const int h = C >> 6, d = C & 63;
            if (mode == 0) {
                u16* ow = (u16*)Out;
                #pragma unroll
                for (int r = 0; r < 4; ++r)
                    ow[(((size_t)(b * NHEAD + h) * SEQN) + nb + r) * DHEAD + d] =
                        f2bf((acc[mi][ni][r] + bb[ni]) * QSCALE);
            } else if (mode == 1) {
                u16* ow = (u16*)Out;
                #pragma unroll
                for (int r = 0; r < 4; ++r)
                    ow[(((size_t)(b * NHEAD + h) * SEQN) + nb + r) * DHEAD + d] =
                        f2bf(acc[mi][ni][r] + bb[ni]);
            } else {
                float* ow = (float*)Out;
                #pragma unroll
                for (int r = 0; r < 4; ++r)
                    ow[(size_t)(Rbase + r) * DIMF + C] = acc[mi][ni][r] + bb[ni];
            }
        }
    }
}

__global__ __launch_bounds__(256, 3)
void qkv_proj(const float* __restrict__ x, const float* __restrict__ src,
              const u16* __restrict__ wqb, const float* __restrict__ bq,
              const u16* __restrict__ wkb, const float* __restrict__ bk,
              const u16* __restrict__ wvb, const float* __restrict__ bv,
              const int* __restrict__ mask,
              u16* __restrict__ qw, u16* __restrict__ kw, u16* __restrict__ vtw)
{
    const int z = blockIdx.z;
    const float* X = (z == 0) ? x : src;
    const u16* W = (z == 0) ? wqb : (z == 1) ? wkb : wvb;
    const float* B = (z == 0) ? bq : (z == 1) ? bk : bv;
    void* O = (z == 0) ? (void*)qw : (z == 1) ? (void*)kw : (void*)vtw;
    gemm_mfma(X, nullptr, W, B, mask, O, z);
}

__global__ __launch_bounds__(256, 3)
void out_proj(const u16* __restrict__ aggb, const u16* __restrict__ wmb,
              const float* __restrict__ bm, float* __restrict__ out)
{
    gemm_mfma(nullptr, aggb, wmb, bm, nullptr, (void*)out, 3);
}

// ---------------------------------------------------------------------------
// MFMA flash attention v12: v10 (R6-proven, KVBLK=128) FATTENED to 512
// threads / 8 waves / 128 q-rows per block, grid 256 = 1 block/CU.
// R7 lesson: fragment-shaped per-lane global loads scatter (16 rows/frag) --
// contiguous global_load_lds + swizzled LDS is the only fast K/V path; the
// v10 DMA/LDS structure is kept verbatim.  What changes: per-CU TLP is the
// same 8 waves, but barrier-convoy events per CU halve (2 blocks x 16 ->
// 1 x 16; R6 measured ~375cy/event) and K/V DMA traffic per CU halves (the
// same 16KB tile now serves 128 q-rows; per-wave DMA issue 8 -> 4 load16).
// Swizzle algebra unchanged: K groups g=wave+8j (rows 8g..8g+7, stored oct
// (l&7)^(dr&7)); V groups g=wave+8j with (4g+vr)&15 = (4*wave+vr)&15 since
// 32j = 0 mod 16 -> reader formulas identical to v10.  Epilogue Osum grows
// to 4 qg x 2048 f32 = 32KB = exactly the dead KsD.
// ---------------------------------------------------------------------------
__global__ __launch_bounds__(512, 2)
void flash_attn_mfma(const u16* __restrict__ q, const u16* __restrict__ k,
                     const u16* __restrict__ vt, const u16* __restrict__ maskbf,
                     u16* __restrict__ agg)
{
    __shared__ __align__(16) u16 KsD[2][8192];    // 2 x 16 KB: 128 rows x 64 u16
    __shared__ __align__(16) u16 VtsD[2][8192];   // 2 x 16 KB: 64 rows x 128 u16
    float* Osum = (float*)&KsD[0][0];             // epilogue union: 32 KB (= KsD)
    float* Lsum = (float*)&VtsD[0][0];            // [qg][32q] = 128 floats

    const int tid  = threadIdx.x;
    const int wave = tid >> 6;                    // 0..7
    const int lane = tid & 63;
    const int l15  = lane & 15;
    const int quad = lane >> 4;
    const int qg = wave >> 1, mh = wave & 1;      // qg 0..3, mh 0..1

    // XCD swizzle: bid&7 = XCD (dispatch round-robins blocks over 8 XCDs)
    const int bid  = blockIdx.x;
    const int xcd  = bid & 7, slot = bid >> 3;        // slot 0..31
    const int pair = (xcd << 1) | (slot & 1);         // (b*8+h) 0..15
    const int b = pair >> 3, h = pair & 7;
    const int n0 = (slot >> 1) * 128;                 // 16 q-tiles of 128

    const size_t hoff = (size_t)(b * NHEAD + h) * (size_t)SEQM * DHEAD;
    const u16* kb = k  + hoff;
    const u16* vb = vt + hoff;
    const u16* mb = maskbf + b * SEQM;

    // DMA source addressing (v10 geometry, 8 waves x 2 groups each)
    const int dr  = lane >> 3;                        // K row-in-group
    const int kct = (lane & 7) ^ (dr & 7);            // K source oct
    const int vr  = lane >> 4;                        // V row-in-group
    const int vct = (lane & 15) ^ ((4 * wave + vr) & 15);  // V source oct
    const u16* kq[2];
    const u16* vq[2];
    #pragma unroll
    for (int j = 0; j < 2; ++j) {
        const int g = wave + 8 * j;
        kq[j] = kb + (size_t)(g * 8 + dr) * DHEAD + kct * 8;
        vq[j] = vb + (size_t)(g * 4 + vr) * SEQM + vct * 8;
    }

    // Q B-frags (prescaled by 0.125*log2e): cols q = n0 + qg*32 + qh*16 + l15
    bf16x8 qf[2][2];
    #pragma unroll
    for (int qh = 0; qh < 2; ++qh) {
        const u16* qp = q + hoff + (size_t)(n0 + qg * 32 + qh * 16 + l15) * DHEAD
                        + quad * 8;
        qf[qh][0] = *(const bf16x8*)qp;
        qf[qh][1] = *(const bf16x8*)(qp + 32);
    }

    // prologue: tile 0 -> buffer 0; mask frags 0 -> registers
    #pragma unroll
    for (int j = 0; j < 2; ++j) {
        load16(kq[j], &KsD[0][(wave + 8 * j) * 512]);
        load16(vq[j], &VtsD[0][(wave + 8 * j) * 512]);
    }
    bf16x8 mfA_nxt = *(const bf16x8*)&mb[64 * mh + quad * 8];
    bf16x8 mfB_nxt = *(const bf16x8*)&mb[64 * mh + 32 + quad * 8];

    f32x4 O[2][4] = {};    // [qh][sd]: row q = quad*4+r, col d = 16*sd+l15
    f32x4 lacc[2] = {};
    const int NT = SEQM / 128;   // 16

    for (int mt = 0; mt < NT; ++mt) {
        const int cur = mt & 1;
        __syncthreads();   // drains vmcnt -> tile mt resident; prior reads done
        bf16x8 mfA = mfA_nxt, mfB = mfB_nxt;
        if (mt + 1 < NT) {
            const size_t m1 = (size_t)(mt + 1) * 128;
            const int nb = cur ^ 1;
            #pragma unroll
            for (int j = 0; j < 2; ++j) {
                load16(kq[j] + m1 * DHEAD, &KsD[nb][(wave + 8 * j) * 512]);
                load16(vq[j] + m1, &VtsD[nb][(wave + 8 * j) * 512]);
            }
            mfA_nxt = *(const bf16x8*)&mb[m1 + 64 * mh + quad * 8];
            mfB_nxt = *(const bf16x8*)&mb[m1 + 64 * mh + 32 + quad * 8];
        }
        const u16* Ks  = KsD[cur];
        const u16* Vts = VtsD[cur];

        // S^T (this wave's 64-m half): st[qh][sub], mrow = 64mh+16sub+l15
        f32x4 st[2][4] = {};
        __builtin_amdgcn_s_setprio(1);
        #pragma unroll
        for (int sub = 0; sub < 4; ++sub) {
            const int mrow = 64 * mh + 16 * sub + l15;
            #pragma unroll
            for (int c = 0; c < 2; ++c) {
                const int oct = (4 * c + quad) ^ (l15 & 7);
                bf16x8 af = *(const bf16x8*)&Ks[mrow * 64 + oct * 8];
                #pragma unroll
                for (int qh = 0; qh < 2; ++qh)
                    st[qh][sub] = __builtin_amdgcn_mfma_f32_16x16x32_bf16(
                        af, qf[qh][c], st[qh][sub], 0, 0, 0);
            }
        }
        __builtin_amdgcn_s_setprio(0);

        // T12 per 32-m group
        bf16x8 pfrA[2], pfrB[2];
        #pragma unroll
        for (int qh = 0; qh < 2; ++qh) {
            pfrA[qh] = t12pack(st[qh][0], st[qh][1]);
            pfrB[qh] = t12pack(st[qh][2], st[qh][3]);
        }

        __builtin_amdgcn_s_setprio(1);
        #pragma unroll
        for (int qh = 0; qh < 2; ++qh) {
            lacc[qh] = __builtin_amdgcn_mfma_f32_16x16x32_bf16(
                pfrA[qh], mfA, lacc[qh], 0, 0, 0);
            lacc[qh] = __builtin_amdgcn_mfma_f32_16x16x32_bf16(
                pfrB[qh], mfB, lacc[qh], 0, 0, 0);
        }
        #pragma unroll
        for (int sd = 0; sd < 4; ++sd) {
            const int pA = (8 * mh + quad) ^ l15;       // stored pos, group A
            const int pB = (8 * mh + 4 + quad) ^ l15;   // stored pos, group B
            bf16x8 vfA = *(const bf16x8*)&Vts[(16 * sd + l15) * 128 + pA * 8];
            bf16x8 vfB = *(const bf16x8*)&Vts[(16 * sd + l15) * 128 + pB * 8];
            #pragma unroll
            for (int qh = 0; qh < 2; ++qh) {
                O[qh][sd] = __builtin_amdgcn_mfma_f32_16x16x32_bf16(
                    pfrA[qh], vfA, O[qh][sd], 0, 0, 0);
                O[qh][sd] = __builtin_amdgcn_mfma_f32_16x16x32_bf16(
                    pfrB[qh], vfB, O[qh][sd], 0, 0, 0);
            }
        }
        __builtin_amdgcn_s_setprio(0);
    }

    // combine m-halves per q-group (LDS unioned over dead KsD/VtsD)
    __syncthreads();
    if (mh == 1) {
        #pragma unroll
        for (int qh = 0; qh < 2; ++qh) {
            #pragma unroll
            for (int sd = 0; sd < 4; ++sd)
                #pragma unroll
                for (int r = 0; r < 4; ++r)
                    Osum[qg * 2048 + (qh * 16 + quad * 4 + r) * 64 + 16 * sd + l15]
                        = O[qh][sd][r];
            if (l15 == 0) {
                #pragma unroll
                for (int r = 0; r < 4; ++r)
                    Lsum[qg * 32 + qh * 16 + quad * 4 + r] = lacc[qh][r];
            }
        }
    }
    __syncthreads();
    if (mh == 0) {
        #pragma unroll
        for (int qh = 0; qh < 2; ++qh)
            #pragma unroll
            for (int r = 0; r < 4; ++r) {
                const float inv = 1.f /
                    (lacc[qh][r] + Lsum[qg * 32 + qh * 16 + quad * 4 + r]);
                const int n = n0 + qg * 32 + qh * 16 + quad * 4 + r;
                u16* ag = agg + ((size_t)b * SEQN + n) * DIMF + h * DHEAD + l15;
                #pragma unroll
                for (int sd = 0; sd < 4; ++sd)
                    ag[16 * sd] = f2bf((O[qh][sd][r] +
                        Osum[qg * 2048 + (qh * 16 + quad * 4 + r) * 64 + 16 * sd + l15])
                        * inv);
            }
    }
}

extern "C" void kernel_launch(void* const* d_in, const int* in_sizes, int n_in,
                              void* d_out, int out_size, void* d_ws, size_t ws_size,
                              hipStream_t stream)
{
    (void)in_sizes; (void)n_in; (void)out_size; (void)ws_size;
    const float* x      = (const float*)d_in[0];
    const float* source = (const float*)d_in[1];
    const int*   mask   = (const int*)  d_in[2];
    const float* Wq = (const float*)d_in[3]; const float* bq = (const float*)d_in[4];
    const float* Wk = (const float*)d_in[5]; const float* bk = (const float*)d_in[6];
    const float* Wv = (const float*)d_in[7]; const float* bv = (const float*)d_in[8];
    const float* Wm = (const float*)d_in[9]; const float* bm = (const float*)d_in[10];
    float* out = (float*)d_out;

    const size_t SZ = (size_t)BATCH * SEQN * DIMF;   // 2,097,152 elems
    const size_t WZ = (size_t)DIMF * DIMF;
    u16* qw   = (u16*)d_ws;          // bf16 [B][H][n][d] (xQSCALE, +bq)
    u16* kw   = qw  + SZ;            // bf16 [B][H][m][d]
    u16* vtw  = kw  + SZ;            // bf16 V^T [B][H][d][m], masked
    u16* aggb = vtw + SZ;            // bf16 [B][n][H*64+d]
    u16* wqb  = aggb + SZ;
    u16* wkb  = wqb + WZ;
    u16* wvb  = wkb + WZ;
    u16* wmb  = wvb + WZ;
    u16* maskbf = wmb + WZ;          // bf16 [B][M] {0,1}; ~19 MB total

    dim3 gcvt((WZ / 4 + 255) / 256, 5);
    cvt_w<<<gcvt, 256, 0, stream>>>(Wq, Wk, Wv, Wm, mask,
                                    wqb, wkb, wvb, wmb, maskbf);

    dim3 gproj(4096 / 64, 512 / 128, 3);    // 768 blocks
    qkv_proj<<<gproj, 256, 0, stream>>>(x, source, wqb, bq, wkb, bk, wvb, bv,
                                        mask, qw, kw, vtw);

    flash_attn_mfma<<<256, 512, 0, stream>>>(qw, kw, vtw, maskbf, aggb);

    dim3 gout(4096 / 64, 512 / 128);        // 256 blocks
    out_proj<<<gout, 256, 0, stream>>>(aggb, wmb, bm, out);
}

// Round 9
// 136.357 us; speedup vs baseline: 1.1049x; 1.0154x over previous
//
#include <hip/hip_runtime.h>
#include <hip/hip_bf16.h>

#define DIMF 512
#define NHEAD 8
#define DHEAD 64
#define BATCH 2
#define SEQN 2048
#define SEQM 2048
#define FPS 40        // padded LDS row stride (u16): 32 data + 8 pad -> 2-way banks
#define QSCALE 0.18033688011112042f   // 0.125 * log2(e)

typedef unsigned short u16;
typedef __attribute__((ext_vector_type(8))) short bf16x8;
typedef __attribute__((ext_vector_type(4))) float f32x4;

static __device__ __forceinline__ u16 f2bf(float f) {
    unsigned u = __float_as_uint(f);
    u += 0x7FFF + ((u >> 16) & 1);      // RNE
    return (u16)(u >> 16);
}

static __device__ __forceinline__
void load16(const u16* g, u16* l) {
    __builtin_amdgcn_global_load_lds(
        (const __attribute__((address_space(1))) void*)g,
        (__attribute__((address_space(3))) void*)l,
        16, 0, 0);
}

// permlane pair: A<32..63> <-> C<0..31>, then A<odd 16-groups> <-> C<even>.
static __device__ __forceinline__
void permpair(unsigned& a, unsigned& c) {
#if __has_builtin(__builtin_amdgcn_permlane32_swap)
    {
        auto r1 = __builtin_amdgcn_permlane32_swap(a, c, false, false);
        unsigned a1 = r1[0], c1 = r1[1];
        auto r2 = __builtin_amdgcn_permlane16_swap(a1, c1, false, false);
        a = r2[0]; c = r2[1];
    }
#else
    asm("v_permlane32_swap_b32 %0, %1" : "+v"(a), "+v"(c));
    asm("v_permlane16_swap_b32 %0, %1" : "+v"(a), "+v"(c));
#endif
}

// T12: two 32-row S^T sub-accumulators -> exp2 -> packed bf16 -> permlane
// route to the PV A-frag layout (verified index-by-index, R3 measured win).
static __device__ __forceinline__
bf16x8 t12pack(f32x4 s0, f32x4 s1) {
    float e00 = __builtin_amdgcn_exp2f(s0[0]);
    float e01 = __builtin_amdgcn_exp2f(s0[1]);
    float e02 = __builtin_amdgcn_exp2f(s0[2]);
    float e03 = __builtin_amdgcn_exp2f(s0[3]);
    float e10 = __builtin_amdgcn_exp2f(s1[0]);
    float e11 = __builtin_amdgcn_exp2f(s1[1]);
    float e12 = __builtin_amdgcn_exp2f(s1[2]);
    float e13 = __builtin_amdgcn_exp2f(s1[3]);
    unsigned a0, a1, c0w, c1w;
    asm("v_cvt_pk_bf16_f32 %0, %1, %2" : "=v"(a0)  : "v"(e00), "v"(e01));
    asm("v_cvt_pk_bf16_f32 %0, %1, %2" : "=v"(a1)  : "v"(e02), "v"(e03));
    asm("v_cvt_pk_bf16_f32 %0, %1, %2" : "=v"(c0w) : "v"(e10), "v"(e11));
    asm("v_cvt_pk_bf16_f32 %0, %1, %2" : "=v"(c1w) : "v"(e12), "v"(e13));
    permpair(a0, c0w);   // a0 = frag w0, c0w = frag w2
    permpair(a1, c1w);   // a1 = frag w1, c1w = frag w3
    union { unsigned u[4]; bf16x8 hv; } pu;
    pu.u[0] = a0; pu.u[1] = a1; pu.u[2] = c0w; pu.u[3] = c1w;
    return pu.hv;
}

// Barrier WITHOUT vmcnt drain (GEMM K-loop: cross-wave data moves via LDS
// only; register-staged global loads are ordered by compiler register deps).
#define LDS_BARRIER() do {                                      \
    asm volatile("s_waitcnt lgkmcnt(0)" ::: "memory");          \
    __builtin_amdgcn_s_barrier();                               \
    __builtin_amdgcn_sched_barrier(0);                          \
} while (0)

// ---------------------------------------------------------------------------
// weights fp32 -> bf16 (+ mask int -> bf16 {0,1})
// ---------------------------------------------------------------------------
__global__ __launch_bounds__(256)
void cvt_w(const float* __restrict__ wq, const float* __restrict__ wk,
           const float* __restrict__ wv, const float* __restrict__ wm,
           const int* __restrict__ mask,
           u16* __restrict__ wqb, u16* __restrict__ wkb,
           u16* __restrict__ wvb, u16* __restrict__ wmb,
           u16* __restrict__ maskbf)
{
    int i = (blockIdx.x * 256 + threadIdx.x) * 4;
    if (blockIdx.y == 4) {
        if (i < BATCH * SEQM) {
            int4 m4 = *(const int4*)&mask[i];
            *(ushort4*)&maskbf[i] = make_ushort4(m4.x ? 0x3F80 : 0, m4.y ? 0x3F80 : 0,
                                                 m4.z ? 0x3F80 : 0, m4.w ? 0x3F80 : 0);
        }
        return;
    }
    const float* in = (blockIdx.y == 0) ? wq : (blockIdx.y == 1) ? wk
                    : (blockIdx.y == 2) ? wv : wm;
    u16* out = (blockIdx.y == 0) ? wqb : (blockIdx.y == 1) ? wkb
             : (blockIdx.y == 2) ? wvb : wmb;
    if (i >= DIMF * DIMF) return;
    float4 v = *(const float4*)&in[i];
    *(ushort4*)&out[i] = make_ushort4(f2bf(v.x), f2bf(v.y), f2bf(v.z), f2bf(v.w));
}

// ---------------------------------------------------------------------------
// bf16 MFMA GEMM (R3-proven): double-buffered, one lgkm-only barrier per
// K-step.  64x128 tile, 4 waves (2x2), wave 32x64 = 2x4 frags.  A from fp32
// (fused cvt) or bf16.  Padded LDS stride 40 u16 (2-way banks).
// mode 0: q -> bf16 [B][H][n][d], (val+bias)*QSCALE (softmax+exp2 folded)
// mode 1: k -> bf16 [B][H][m][d]
// mode 2: V^T -> bf16 [B][H][d][m], masked rows zeroed, transposed in-block
// mode 3: fp32 row-major [4096][512]
// ---------------------------------------------------------------------------
#define ASZ (64 * FPS)
#define BSZ (128 * FPS)

__device__ __forceinline__
void gemm_mfma(const float* __restrict__ Xf, const u16* __restrict__ Xb,
               const u16* __restrict__ W, const float* __restrict__ bias,
               const int* __restrict__ msk, void* __restrict__ Out, int mode)
{
    __shared__ __align__(16) u16 SH[2 * ASZ + 2 * BSZ];   // 30 KB

    const int tid  = threadIdx.x;
    const int wave = tid >> 6;
    const int lane = tid & 63;
    const int l15  = lane & 15;
    const int quad = lane >> 4;
    const int wm = wave & 1, wn = wave >> 1;
    const int r0 = blockIdx.x * 64, c0 = blockIdx.y * 128;

    f32x4 acc[2][4] = {};

    const int br = tid >> 2, boct = tid & 3;        // B: rows br, br+64
    const int ar = tid >> 3, aseg = tid & 7;        // A fp32: rows ar, ar+32

    bf16x8 rb0, rb1, rab;
    float4 ra0, ra1;

    auto loadg = [&](int k0) {
        rb0 = *(const bf16x8*)&W[(size_t)(c0 + br) * DIMF + k0 + boct * 8];
        rb1 = *(const bf16x8*)&W[(size_t)(c0 + br + 64) * DIMF + k0 + boct * 8];
        if (Xf) {
            ra0 = *(const float4*)&Xf[(size_t)(r0 + ar) * DIMF + k0 + aseg * 4];
            ra1 = *(const float4*)&Xf[(size_t)(r0 + ar + 32) * DIMF + k0 + aseg * 4];
        } else {
            rab = *(const bf16x8*)&Xb[(size_t)(r0 + br) * DIMF + k0 + boct * 8];
        }
    };
    auto stage = [&](int buf) {
        u16* As = SH + buf * ASZ;
        u16* Bs = SH + 2 * ASZ + buf * BSZ;
        if (Xf) {
            *(ushort4*)&As[ar * FPS + aseg * 4] =
                make_ushort4(f2bf(ra0.x), f2bf(ra0.y), f2bf(ra0.z), f2bf(ra0.w));
            *(ushort4*)&As[(ar + 32) * FPS + aseg * 4] =
                make_ushort4(f2bf(ra1.x), f2bf(ra1.y), f2bf(ra1.z), f2bf(ra1.w));
        } else {
            *(bf16x8*)&As[br * FPS + boct * 8] = rab;
        }
        *(bf16x8*)&Bs[br * FPS + boct * 8] = rb0;
        *(bf16x8*)&Bs[(br + 64) * FPS + boct * 8] = rb1;
    };

    loadg(0);
    stage(0);
    loadg(32);
    LDS_BARRIER();

    const int NK = DIMF / 32;   // 16
    for (int kt = 0; kt < NK; ++kt) {
        const int cur = kt & 1;
        if (kt + 1 < NK) stage(cur ^ 1);       // regs for kt+1 (vmcnt per-reg)
        if (kt + 2 < NK) loadg((kt + 2) * 32); // rides through next barrier
        const u16* As = SH + cur * ASZ;
        const u16* Bs = SH + 2 * ASZ + cur * BSZ;

        bf16x8 af[2], bf[4];
        #pragma unroll
        for (int mi = 0; mi < 2; ++mi)
            af[mi] = *(const bf16x8*)&As[(wm * 32 + mi * 16 + l15) * FPS + quad * 8];
        #pragma unroll
        for (int ni = 0; ni < 4; ++ni)
            bf[ni] = *(const bf16x8*)&Bs[(wn * 64 + ni * 16 + l15) * FPS + quad * 8];
        #pragma unroll
        for (int mi = 0; mi < 2; ++mi)
            #pragma unroll
            for (int ni = 0; ni < 4; ++ni)
                acc[mi][ni] = __builtin_amdgcn_mfma_f32_16x16x32_bf16(
                    af[mi], bf[ni], acc[mi][ni], 0, 0, 0);
        LDS_BARRIER();   // lgkm-only: buf[cur] reads done, buf[cur^1] full
    }

    float bb[4];
    #pragma unroll
    for (int ni = 0; ni < 4; ++ni)
        bb[ni] = bias[c0 + wn * 64 + ni * 16 + l15];

    if (mode == 2) {
        u16* T = SH;                         // 64 x 72 u16 (9 KB of 30)
        const int b = r0 >> 11;
        const int n_base = r0 & (SEQN - 1);
        #pragma unroll
        for (int hh = 0; hh < 2; ++hh) {
            __syncthreads();
            if (wn == hh) {
                #pragma unroll
                for (int mi = 0; mi < 2; ++mi) {
                    const int rl = wm * 32 + mi * 16 + quad * 4;
                    int4 m4 = *(const int4*)&msk[b * SEQM + n_base + rl];
                    float mm[4];
                    mm[0] = m4.x ? 1.f : 0.f; mm[1] = m4.y ? 1.f : 0.f;
                    mm[2] = m4.z ? 1.f : 0.f; mm[3] = m4.w ? 1.f : 0.f;
                    #pragma unroll
                    for (int ni = 0; ni < 4; ++ni)
                        #pragma unroll
                        for (int r = 0; r < 4; ++r)
                            T[(rl + r) * 72 + ni * 16 + l15] =
                                f2bf((acc[mi][ni][r] + bb[ni]) * mm[r]);
                }
            }
            __syncthreads();
            const int d = tid >> 2, ms = (tid & 3) << 4;
            u16 tmp[16];
            #pragma unroll
            for (int j = 0; j < 16; ++j) tmp[j] = T[(ms + j) * 72 + d];
            const int hgl = (c0 >> 6) + hh;
            u16* dst = (u16*)Out + ((size_t)(b * NHEAD + hgl) * DHEAD + d) * SEQM
                       + n_base + ms;
            *(bf16x8*)&dst[0] = *(bf16x8*)&tmp[0];
            *(bf16x8*)&dst[8] = *(bf16x8*)&tmp[8];
        }
        return;
    }

    #pragma unroll
    for (int mi = 0; mi < 2; ++mi) {
        const int Rbase = r0 + wm * 32 + mi * 16 + quad * 4;   // +r, r=0..3
        const int b = Rbase >> 11;
        const int nb = Rbase & (SEQN - 1);
        #pragma unroll
        for (int ni = 0; ni < 4; ++ni) {
            const int C = c0 + wn * 64 + ni * 16 + l15;
            const int h = C >> 6, d = C & 63;
            if (mode == 0) {
                u16* ow = (u16*)Out;
                #pragma unroll
                for (int r = 0; r < 4; ++r)
                    ow[(((size_t)(b * NHEAD + h) * SEQN) + nb + r) * DHEAD + d] =
                        f2bf((acc[mi][ni][r] + bb[ni]) * QSCALE);
            } else if (mode == 1) {
                u16* ow = (u16*)Out;
                #pragma unroll
                for (int r = 0; r < 4; ++r)
                    ow[(((size_t)(b * NHEAD + h) * SEQN) + nb + r) * DHEAD + d] =
                        f2bf(acc[mi][ni][r] + bb[ni]);
            } else {
                float* ow = (float*)Out;
                #pragma unroll
                for (int r = 0; r < 4; ++r)
                    ow[(size_t)(Rbase + r) * DIMF + C] = acc[mi][ni][r] + bb[ni];
            }
        }
    }
}

__global__ __launch_bounds__(256, 3)
void qkv_proj(const float* __restrict__ x, const float* __restrict__ src,
              const u16* __restrict__ wqb, const float* __restrict__ bq,
              const u16* __restrict__ wkb, const float* __restrict__ bk,
              const u16* __restrict__ wvb, const float* __restrict__ bv,
              const int* __restrict__ mask,
              u16* __restrict__ qw, u16* __restrict__ kw, u16* __restrict__ vtw)
{
    const int z = blockIdx.z;
    const float* X = (z == 0) ? x : src;
    const u16* W = (z == 0) ? wqb : (z == 1) ? wkb : wvb;
    const float* B = (z == 0) ? bq : (z == 1) ? bk : bv;
    void* O = (z == 0) ? (void*)qw : (z == 1) ? (void*)kw : (void*)vtw;
    gemm_mfma(X, nullptr, W, B, mask, O, z);
}

__global__ __launch_bounds__(256, 3)
void out_proj(const u16* __restrict__ aggb, const u16* __restrict__ wmb,
              const float* __restrict__ bm, float* __restrict__ out)
{
    gemm_mfma(nullptr, aggb, wmb, bm, nullptr, (void*)out, 3);
}

// ---------------------------------------------------------------------------
// MFMA flash attention v10 (FINAL, best measured: 137.7us total).  KVBLK=128,
// 2-deep DMA double-buffer, one vmcnt-draining __syncthreads per 128-m tile.
// Ledger: T12 in-register P (R3, -9us) and KVBLK=128 (R6, -2.5us) are the
// wins; counted-vmcnt (R1), split-m x2 (R4), barrier-free global->reg (R5),
// V-direct-from-global (R7), and 8-wave fat block (R8) all measured
// neutral-to-negative.  R4+R8 bracket: insensitive to blocks/CU AND to
// barrier-event count below this level -- the residual ~2500cy/wave-iter vs
// ~600cy pipe work is intra-chain latency exposure, the attn analog of the
// documented m97 HIP-source barrier-drain ceiling.
// DMA geometry: K tile 128 rows x 128B, groups of 8 rows (1KB), lane l ->
// row 8g+(l>>3), stored pos l&7 holds source oct (l&7)^(row&7).  V^T tile
// 64 rows x 256B, groups of 4 rows (1KB), lane l -> row 4g+(l>>4), stored
// pos l&15 holds source oct (l&15)^(row&15).  Readers XOR the same terms
// back -> bank-conflict <= 2-way.  T12 per 32-m group: subs{0,1} -> pfrA,
// subs{2,3} -> pfrB; PV and mask-row MFMA accumulate both groups.
// ---------------------------------------------------------------------------
__global__ __launch_bounds__(256, 2)
void flash_attn_mfma(const u16* __restrict__ q, const u16* __restrict__ k,
                     const u16* __restrict__ vt, const u16* __restrict__ maskbf,
                     u16* __restrict__ agg)
{
    __shared__ __align__(16) u16 KsD[2][8192];    // 2 x 16 KB: 128 rows x 64 u16
    __shared__ __align__(16) u16 VtsD[2][8192];   // 2 x 16 KB: 64 rows x 128 u16
    float* Osum = (float*)&KsD[0][0];             // epilogue union (16 KB)
    float* Lsum = (float*)&VtsD[0][0];            // [qg][32q]

    const int tid  = threadIdx.x;
    const int wave = tid >> 6;
    const int lane = tid & 63;
    const int l15  = lane & 15;
    const int quad = lane >> 4;
    const int qg = wave >> 1, mh = wave & 1;

    // XCD swizzle: bid&7 = XCD (dispatch round-robins blocks over 8 XCDs)
    const int bid  = blockIdx.x;
    const int xcd  = bid & 7, slot = bid >> 3;        // slot 0..63
    const int pair = (xcd << 1) | (slot & 1);         // (b*8+h) 0..15
    const int b = pair >> 3, h = pair & 7;
    const int n0 = (slot >> 1) * 64;

    const size_t hoff = (size_t)(b * NHEAD + h) * (size_t)SEQM * DHEAD;
    const u16* kb = k  + hoff;
    const u16* vb = vt + hoff;
    const u16* mb = maskbf + b * SEQM;

    // DMA source addressing (see header comment)
    const int dr  = lane >> 3;                        // K row-in-group
    const int kct = (lane & 7) ^ (dr & 7);            // K source oct
    const int vr  = lane >> 4;                        // V row-in-group
    const int vct = (lane & 15) ^ ((4 * wave + vr) & 15);  // V source oct
    const u16* kq[4];
    const u16* vq[4];
    #pragma unroll
    for (int j = 0; j < 4; ++j) {
        const int g = wave + 4 * j;
        kq[j] = kb + (size_t)(g * 8 + dr) * DHEAD + kct * 8;
        vq[j] = vb + (size_t)(g * 4 + vr) * SEQM + vct * 8;
    }

    // Q B-frags (prescaled by 0.125*log2e): cols q = n0 + qg*32 + qh*16 + l15
    bf16x8 qf[2][2];
    #pragma unroll
    for (int qh = 0; qh < 2; ++qh) {
        const u16* qp = q + hoff + (size_t)(n0 + qg * 32 + qh * 16 + l15) * DHEAD
                        + quad * 8;
        qf[qh][0] = *(const bf16x8*)qp;
        qf[qh][1] = *(const bf16x8*)(qp + 32);
    }

    // prologue: tile 0 -> buffer 0; mask frags 0 -> registers
    #pragma unroll
    for (int j = 0; j < 4; ++j) {
        load16(kq[j], &KsD[0][(wave + 4 * j) * 512]);
        load16(vq[j], &VtsD[0][(wave + 4 * j) * 512]);
    }
    bf16x8 mfA_nxt = *(const bf16x8*)&mb[64 * mh + quad * 8];
    bf16x8 mfB_nxt = *(const bf16x8*)&mb[64 * mh + 32 + quad * 8];

    f32x4 O[2][4] = {};    // [qh][sd]: row q = quad*4+r, col d = 16*sd+l15
    f32x4 lacc[2] = {};
    const int NT = SEQM / 128;   // 16

    for (int mt = 0; mt < NT; ++mt) {
        const int cur = mt & 1;
        __syncthreads();   // drains vmcnt -> tile mt resident; prior reads done
        bf16x8 mfA = mfA_nxt, mfB = mfB_nxt;
        if (mt + 1 < NT) {
            const size_t m1 = (size_t)(mt + 1) * 128;
            const int nb = cur ^ 1;
            #pragma unroll
            for (int j = 0; j < 4; ++j) {
                load16(kq[j] + m1 * DHEAD, &KsD[nb][(wave + 4 * j) * 512]);
                load16(vq[j] + m1, &VtsD[nb][(wave + 4 * j) * 512]);
            }
            mfA_nxt = *(const bf16x8*)&mb[m1 + 64 * mh + quad * 8];
            mfB_nxt = *(const bf16x8*)&mb[m1 + 64 * mh + 32 + quad * 8];
        }
        const u16* Ks  = KsD[cur];
        const u16* Vts = VtsD[cur];

        // S^T (this wave's 64-m half): st[qh][sub], mrow = 64mh+16sub+l15
        f32x4 st[2][4] = {};
        __builtin_amdgcn_s_setprio(1);
        #pragma unroll
        for (int sub = 0; sub < 4; ++sub) {
            const int mrow = 64 * mh + 16 * sub + l15;
            #pragma unroll
            for (int c = 0; c < 2; ++c) {
                const int oct = (4 * c + quad) ^ (l15 & 7);
                bf16x8 af = *(const bf16x8*)&Ks[mrow * 64 + oct * 8];
                #pragma unroll
                for (int qh = 0; qh < 2; ++qh)
                    st[qh][sub] = __builtin_amdgcn_mfma_f32_16x16x32_bf16(
                        af, qf[qh][c], st[qh][sub], 0, 0, 0);
            }
        }
        __builtin_amdgcn_s_setprio(0);

        // T12 per 32-m group
        bf16x8 pfrA[2], pfrB[2];
        #pragma unroll
        for (int qh = 0; qh < 2; ++qh) {
            pfrA[qh] = t12pack(st[qh][0], st[qh][1]);
            pfrB[qh] = t12pack(st[qh][2], st[qh][3]);
        }

        __builtin_amdgcn_s_setprio(1);
        #pragma unroll
        for (int qh = 0; qh < 2; ++qh) {
            lacc[qh] = __builtin_amdgcn_mfma_f32_16x16x32_bf16(
                pfrA[qh], mfA, lacc[qh], 0, 0, 0);
            lacc[qh] = __builtin_amdgcn_mfma_f32_16x16x32_bf16(
                pfrB[qh], mfB, lacc[qh], 0, 0, 0);
        }
        #pragma unroll
        for (int sd = 0; sd < 4; ++sd) {
            const int pA = (8 * mh + quad) ^ l15;       // stored pos, group A
            const int pB = (8 * mh + 4 + quad) ^ l15;   // stored pos, group B
            bf16x8 vfA = *(const bf16x8*)&Vts[(16 * sd + l15) * 128 + pA * 8];
            bf16x8 vfB = *(const bf16x8*)&Vts[(16 * sd + l15) * 128 + pB * 8];
            #pragma unroll
            for (int qh = 0; qh < 2; ++qh) {
                O[qh][sd] = __builtin_amdgcn_mfma_f32_16x16x32_bf16(
                    pfrA[qh], vfA, O[qh][sd], 0, 0, 0);
                O[qh][sd] = __builtin_amdgcn_mfma_f32_16x16x32_bf16(
                    pfrB[qh], vfB, O[qh][sd], 0, 0, 0);
            }
        }
        __builtin_amdgcn_s_setprio(0);
    }

    // combine m-halves per q-group (LDS unioned over dead Ks/Vts)
    __syncthreads();
    if (mh == 1) {
        #pragma unroll
        for (int qh = 0; qh < 2; ++qh) {
            #pragma unroll
            for (int sd = 0; sd < 4; ++sd)
                #pragma unroll
                for (int r = 0; r < 4; ++r)
                    Osum[qg * 2048 + (qh * 16 + quad * 4 + r) * 64 + 16 * sd + l15]
                        = O[qh][sd][r];
            if (l15 == 0) {
                #pragma unroll
                for (int r = 0; r < 4; ++r)
                    Lsum[qg * 32 + qh * 16 + quad * 4 + r] = lacc[qh][r];
            }
        }
    }
    __syncthreads();
    if (mh == 0) {
        #pragma unroll
        for (int qh = 0; qh < 2; ++qh)
            #pragma unroll
            for (int r = 0; r < 4; ++r) {
                const float inv = 1.f /
                    (lacc[qh][r] + Lsum[qg * 32 + qh * 16 + quad * 4 + r]);
                const int n = n0 + qg * 32 + qh * 16 + quad * 4 + r;
                u16* ag = agg + ((size_t)b * SEQN + n) * DIMF + h * DHEAD + l15;
                #pragma unroll
                for (int sd = 0; sd < 4; ++sd)
                    ag[16 * sd] = f2bf((O[qh][sd][r] +
                        Osum[qg * 2048 + (qh * 16 + quad * 4 + r) * 64 + 16 * sd + l15])
                        * inv);
            }
    }
}

extern "C" void kernel_launch(void* const* d_in, const int* in_sizes, int n_in,
                              void* d_out, int out_size, void* d_ws, size_t ws_size,
                              hipStream_t stream)
{
    (void)in_sizes; (void)n_in; (void)out_size; (void)ws_size;
    const float* x      = (const float*)d_in[0];
    const float* source = (const float*)d_in[1];
    const int*   mask   = (const int*)  d_in[2];
    const float* Wq = (const float*)d_in[3]; const float* bq = (const float*)d_in[4];
    const float* Wk = (const float*)d_in[5]; const float* bk = (const float*)d_in[6];
    const float* Wv = (const float*)d_in[7]; const float* bv = (const float*)d_in[8];
    const float* Wm = (const float*)d_in[9]; const float* bm = (const float*)d_in[10];
    float* out = (float*)d_out;

    const size_t SZ = (size_t)BATCH * SEQN * DIMF;   // 2,097,152 elems
    const size_t WZ = (size_t)DIMF * DIMF;
    u16* qw   = (u16*)d_ws;          // bf16 [B][H][n][d] (xQSCALE, +bq)
    u16* kw   = qw  + SZ;            // bf16 [B][H][m][d]
    u16* vtw  = kw  + SZ;            // bf16 V^T [B][H][d][m], masked
    u16* aggb = vtw + SZ;            // bf16 [B][n][H*64+d]
    u16* wqb  = aggb + SZ;
    u16* wkb  = wqb + WZ;
    u16* wvb  = wkb + WZ;
    u16* wmb  = wvb + WZ;
    u16* maskbf = wmb + WZ;          // bf16 [B][M] {0,1}; ~19 MB total

    dim3 gcvt((WZ / 4 + 255) / 256, 5);
    cvt_w<<<gcvt, 256, 0, stream>>>(Wq, Wk, Wv, Wm, mask,
                                    wqb, wkb, wvb, wmb, maskbf);

    dim3 gproj(4096 / 64, 512 / 128, 3);    // 768 blocks
    qkv_proj<<<gproj, 256, 0, stream>>>(x, source, wqb, bq, wkb, bk, wvb, bv,
                                        mask, qw, kw, vtw);

    flash_attn_mfma<<<512, 256, 0, stream>>>(qw, kw, vtw, maskbf, aggb);

    dim3 gout(4096 / 64, 512 / 128);        // 256 blocks
    out_proj<<<gout, 256, 0, stream>>>(aggb, wmb, bm, out);
}